// Round 16
// baseline (165.613 us; speedup 1.0000x reference)
//
#include <hip/hip_runtime.h>
#include <hip/hip_bf16.h>
#include <math.h>

#define N_NODES 10000
#define IN_F 512
#define OUT_F 512
#define N_EDGES 160000
#define K_SPLINE 4096   // 512 dims * 8 basis fns
#define K_TOTAL 4608    // + 512 silu(base) slots
#define NBK 144         // K fragment-blocks (4608/32)
#define NBM 628         // M fragment-blocks (157 tiles * 4)
#define ALPHA 0.2f

typedef __attribute__((ext_vector_type(8))) short short8;
typedef __attribute__((ext_vector_type(4))) float f32x4;
typedef unsigned short ushort_t;
typedef unsigned long long u64;

__device__ __forceinline__ unsigned bfpair(float a, float b) {
    __hip_bfloat162 h2 = __float22bfloat162_rn(make_float2(a, b));
    return *reinterpret_cast<unsigned*>(&h2);
}
__device__ __forceinline__ float bflo(unsigned u) { return __uint_as_float(u << 16); }
__device__ __forceinline__ float bfhi(unsigned u) { return __uint_as_float(u & 0xffff0000u); }

__device__ __forceinline__ float silu_f(float x) {
    return x / (1.f + __expf(-x));
}

// spline window: 8 packed bf16 (one-hot shifted cubic pieces) for scalar x
__device__ __forceinline__ uint4 spline_window(float x) {
    float xc = (x + 2.2f) * 2.5f;
    float fc = floorf(xc);
    int c = (int)fc;
    float u = xc - fc;
    float omu = 1.f - u;
    float u2 = u * u, u3 = u2 * u;
    float n0 = (1.f / 6.f) * omu * omu * omu;
    float n1 = 0.5f * u3 - u2 + (2.f / 3.f);
    float n2 = -0.5f * u3 + 0.5f * u2 + 0.5f * u + (1.f / 6.f);
    float n3 = (1.f / 6.f) * u3;
    u64 V = (u64)bfpair(n0, n1) | ((u64)bfpair(n2, n3) << 32);
    int sh = (c - 3) * 16;
    u64 lo, hi;
    if (c < 0 || c > 10)    { lo = 0; hi = 0; }
    else if (sh >= 64)      { lo = 0; hi = V << (sh - 64); }
    else if (sh > 0)        { lo = V << sh; hi = V >> (64 - sh); }
    else if (sh == 0)       { lo = V; hi = 0; }
    else                    { lo = V >> (-sh); hi = 0; }
    uint4 pk;
    pk.x = (unsigned)lo; pk.y = (unsigned)(lo >> 32);
    pk.z = (unsigned)hi; pk.w = (unsigned)(hi >> 32);
    return pk;
}

// ---------------- K0: wa projections ----------------
__global__ void wa_kernel(const float* __restrict__ W, const float* __restrict__ a,
                          float* __restrict__ wa0, float* __restrict__ wa1) {
    int b = blockIdx.x;
    int tid = threadIdx.x;
    int w = tid >> 6, l = tid & 63;
    int i = b * 4 + w;
    float s0 = 0.f, s1 = 0.f;
    #pragma unroll
    for (int oo = 0; oo < 8; ++oo) {
        int o = l + oo * 64;
        float wv = W[(size_t)i * OUT_F + o];
        s0 += wv * a[o];
        s1 += wv * a[OUT_F + o];
    }
    #pragma unroll
    for (int off = 32; off > 0; off >>= 1) {
        s0 += __shfl_down(s0, off, 64);
        s1 += __shfl_down(s1, off, 64);
    }
    if (l == 0) { wa0[i] = s0; wa1[i] = s1; }
}

// ---------------- K1: fused deg-hist + (hcast & s,t projections) + packB ----------------
__global__ void fused1_kernel(const float* __restrict__ h, ushort_t* __restrict__ hb,
                              const float* __restrict__ wa0, const float* __restrict__ wa1,
                              float* __restrict__ s, float* __restrict__ t,
                              const float* __restrict__ base_w, const float* __restrict__ spline_w,
                              ushort_t* __restrict__ Bt,
                              const int* __restrict__ ei, int* __restrict__ deg) {
    int b = blockIdx.x;
    int tid = threadIdx.x;
    if (b < 625) {
        int k = b * 256 + tid;
        if (k < N_EDGES) atomicAdd(&deg[ei[k]], 1);
    } else if (b < 3125) {
        int bb = b - 625;
        int w = tid >> 6, l = tid & 63;
        int n = bb * 4 + w;
        const float* hp = h + (size_t)n * IN_F + l * 8;
        float4 x0 = *(const float4*)hp;
        float4 x1 = *(const float4*)(hp + 4);
        uint4 pk;
        pk.x = bfpair(x0.x, x0.y);
        pk.y = bfpair(x0.z, x0.w);
        pk.z = bfpair(x1.x, x1.y);
        pk.w = bfpair(x1.z, x1.w);
        *(uint4*)(hb + (size_t)n * IN_F + l * 8) = pk;
        const float4* w0 = (const float4*)(wa0 + l * 8);
        const float4* w1 = (const float4*)(wa1 + l * 8);
        float4 a0 = w0[0], a1 = w0[1];
        float4 b0 = w1[0], b1 = w1[1];
        float ss = x0.x*a0.x + x0.y*a0.y + x0.z*a0.z + x0.w*a0.w
                 + x1.x*a1.x + x1.y*a1.y + x1.z*a1.z + x1.w*a1.w;
        float tt = x0.x*b0.x + x0.y*b0.y + x0.z*b0.z + x0.w*b0.w
                 + x1.x*b1.x + x1.y*b1.y + x1.z*b1.z + x1.w*b1.w;
        #pragma unroll
        for (int o = 32; o > 0; o >>= 1) {
            ss += __shfl_down(ss, o, 64);
            tt += __shfl_down(tt, o, 64);
        }
        if (l == 0) { s[n] = ss; t[n] = tt; }
    } else {
        int gid = (b - 3125) * 256 + tid;       // 294912 = 512 o * 576 kb8
        int o = gid / 576;
        int kb8 = gid - o * 576;
        int k0 = kb8 * 8;
        float4 x0, x1;
        if (k0 < K_SPLINE) {
            const float4* p = (const float4*)(spline_w + (size_t)o * K_SPLINE + k0);
            x0 = p[0]; x1 = p[1];
        } else {
            const float4* p = (const float4*)(base_w + (size_t)o * IN_F + (k0 - K_SPLINE));
            x0 = p[0]; x1 = p[1];
        }
        int frag = (k0 >> 5) * 32 + (o >> 4);
        int lane = ((kb8 & 3) << 4) + (o & 15);
        uint4 pk;
        pk.x = bfpair(x0.x, x0.y);
        pk.y = bfpair(x0.z, x0.w);
        pk.z = bfpair(x1.x, x1.y);
        pk.w = bfpair(x1.z, x1.w);
        *(uint4*)(Bt + ((size_t)frag * 64 + lane) * 8) = pk;
    }
}

// ---------------- K2: one-block exclusive scan over degrees ----------------
__global__ void scan_kernel(const int* __restrict__ deg, int* __restrict__ off,
                            int* __restrict__ cursor) {
    __shared__ int sb[256];
    int tid = threadIdx.x;
    int d[40];
    int tot = 0;
    #pragma unroll
    for (int j = 0; j < 40; ++j) {
        int idx = tid * 40 + j;
        d[j] = (idx < N_NODES) ? deg[idx] : 0;
        tot += d[j];
    }
    sb[tid] = tot;
    __syncthreads();
    for (int sd = 1; sd < 256; sd <<= 1) {
        int v = (tid >= sd) ? sb[tid - sd] : 0;
        __syncthreads();
        sb[tid] += v;
        __syncthreads();
    }
    int run = (tid > 0) ? sb[tid - 1] : 0;
    #pragma unroll
    for (int j = 0; j < 40; ++j) {
        int idx = tid * 40 + j;
        if (idx < N_NODES) { off[idx] = run; cursor[idx] = run; }
        run += d[j];
    }
    if (tid == 255) off[N_NODES] = sb[255];
}

// ---------------- K3: fill CSR ----------------
__global__ void fill_kernel(const int* __restrict__ ei, int* __restrict__ cursor,
                            int* __restrict__ csr_col) {
    int k = blockIdx.x * 256 + threadIdx.x;
    if (k < N_EDGES) {
        int r = ei[k];
        int c = ei[N_EDGES + k];
        int p = atomicAdd(&cursor[r], 1);
        csr_col[p] = c;
    }
}

// ---------------- K4: segment softmax + aggregation, wave-per-node, 4-way edge split ----------------
// Gather: lanes l>>4 ∈ {0..3} each serve edge 4j+ql; each lane owns 32
// features (64B contiguous). Serial chain = ceil(deg/4); unroll 2 keeps 8
// gathers in flight. Merge via shfl_xor(16) + shfl_xor(32).
__global__ __launch_bounds__(256) void agg_kernel(
    const ushort_t* __restrict__ hb, const float* __restrict__ s,
    const float* __restrict__ t, const int* __restrict__ off,
    const int* __restrict__ csr, float* __restrict__ agg) {
    int w = threadIdx.x >> 6, l = threadIdx.x & 63;
    int n = blockIdx.x * 4 + w;
    int e0 = off[n], e1 = off[n + 1];
    float sn = s[n];

    float m = -1e30f, den = 0.f;
    for (int k = e0 + l; k < e1; k += 64) {
        float v = sn + t[csr[k]];
        v = (v >= 0.f) ? v : ALPHA * v;
        float mn = fmaxf(m, v);
        den = den * __expf(m - mn) + __expf(v - mn);
        m = mn;
    }
    #pragma unroll
    for (int o = 1; o < 64; o <<= 1) {
        float m2 = __shfl_xor(m, o, 64);
        float d2 = __shfl_xor(den, o, 64);
        float mn = fmaxf(m, m2);
        den = den * __expf(m - mn) + d2 * __expf(m2 - mn);
        m = mn;
    }
    float inv = (den > 0.f) ? 1.f / den : 0.f;

    int ql = l >> 4;                 // which edge of the quad this lane serves
    int lo = l & 15;                 // feature group: bf16 features [lo*32, lo*32+32)
    float acc[32];
    #pragma unroll
    for (int i = 0; i < 32; ++i) acc[i] = 0.f;
    const ushort_t* hbl = hb + lo * 32;

    for (int base = e0; base < e1; base += 64) {
        int cnt = e1 - base; if (cnt > 64) cnt = 64;
        int c = 0; float att = 0.f;
        if (l < cnt) {
            c = csr[base + l];
            float v = sn + t[c];
            v = (v >= 0.f) ? v : ALPHA * v;
            att = __expf(v - m) * inv;   // lanes >= cnt keep att = 0
        }
        int nquad = (cnt + 3) >> 2;
        #pragma unroll 2
        for (int j = 0; j < nquad; ++j) {
            int e = 4 * j + ql;          // <= 63 always
            float aj = __shfl(att, e, 64);   // 0 when e >= cnt
            int cj = __shfl(c, e, 64);
            const ushort_t* rp = hbl + (size_t)cj * IN_F;
            uint4 u[4];
            u[0] = *(const uint4*)rp;
            u[1] = *(const uint4*)(rp + 8);
            u[2] = *(const uint4*)(rp + 16);
            u[3] = *(const uint4*)(rp + 24);
            #pragma unroll
            for (int q = 0; q < 4; ++q) {
                acc[q * 8 + 0] = fmaf(aj, bflo(u[q].x), acc[q * 8 + 0]);
                acc[q * 8 + 1] = fmaf(aj, bfhi(u[q].x), acc[q * 8 + 1]);
                acc[q * 8 + 2] = fmaf(aj, bflo(u[q].y), acc[q * 8 + 2]);
                acc[q * 8 + 3] = fmaf(aj, bfhi(u[q].y), acc[q * 8 + 3]);
                acc[q * 8 + 4] = fmaf(aj, bflo(u[q].z), acc[q * 8 + 4]);
                acc[q * 8 + 5] = fmaf(aj, bfhi(u[q].z), acc[q * 8 + 5]);
                acc[q * 8 + 6] = fmaf(aj, bflo(u[q].w), acc[q * 8 + 6]);
                acc[q * 8 + 7] = fmaf(aj, bfhi(u[q].w), acc[q * 8 + 7]);
            }
        }
    }
    // merge the four lane-quarters (same features, different edge subsets)
    #pragma unroll
    for (int i = 0; i < 32; ++i) {
        acc[i] += __shfl_xor(acc[i], 16, 64);
        acc[i] += __shfl_xor(acc[i], 32, 64);
    }

    if (ql == 0) {
        float* arow = agg + (size_t)n * IN_F + lo * 32;
        #pragma unroll
        for (int q = 0; q < 8; ++q)
            *(float4*)(arow + q * 4) = make_float4(acc[q * 4 + 0], acc[q * 4 + 1],
                                                   acc[q * 4 + 2], acc[q * 4 + 3]);
    }
}

// ---------------- K5: LDS-staged expansion -> fragment-packed bf16 A ----------------
__global__ __launch_bounds__(256) void expand_kernel(const float* __restrict__ agg,
                                                     ushort_t* __restrict__ Xf) {
    __shared__ float AL[16][516];   // 33 KB; stride 516 keeps reads conflict-light
    int nb = blockIdx.x;
    int tid = threadIdx.x;

    #pragma unroll
    for (int i = 0; i < 8; ++i) {
        int idx = i * 256 + tid;        // 0..2047 float4 slots
        int r = idx >> 7, c4 = idx & 127;
        int n = nb * 16 + r;
        float4 v = (n < N_NODES) ? ((const float4*)(agg + (size_t)n * IN_F))[c4]
                                 : make_float4(0.f, 0.f, 0.f, 0.f);
        *(float4*)&AL[r][c4 * 4] = v;
    }
    __syncthreads();

    int w = tid >> 6, l = tid & 63;
    bool live = (nb * 16 + (l & 15)) < N_NODES;
    #pragma unroll 1
    for (int i = 0; i < 36; ++i) {
        int kb = w + 4 * i;             // wave w covers kb ≡ w (mod 4)
        uint4 pk = make_uint4(0u, 0u, 0u, 0u);
        if (live) {
            if (kb < 128) {
                int dim = kb * 4 + (l >> 4);
                pk = spline_window(AL[l & 15][dim]);
            } else {
                const float* ap = &AL[l & 15][(kb - 128) * 32 + (l >> 4) * 8];
                float4 x0 = *(const float4*)ap;
                float4 x1 = *(const float4*)(ap + 4);
                pk.x = bfpair(silu_f(x0.x), silu_f(x0.y));
                pk.y = bfpair(silu_f(x0.z), silu_f(x0.w));
                pk.z = bfpair(silu_f(x1.x), silu_f(x1.y));
                pk.w = bfpair(silu_f(x1.z), silu_f(x1.w));
            }
        }
        *(uint4*)(Xf + ((size_t)(nb * NBK + kb) * 64 + l) * 8) = pk;
    }
}

// ---------------- K6: streaming GEMM, BK=128, 2-phase double buffer (measured-best) ----------------
// BM=64, BN=128, 4 waves; 36 K-steps of 128; A via global_load_lds (16B);
// B direct L2->reg. Grid 640, R6 decode. 62.9-63.0 us across R6/R10-R15;
// bracketed by: counted-vmcnt (neutral), K-split (net loss), BM=32 (+28%),
// stripe decodes (+23..90%), BK=64 (+4%). Structural plateau for this shape.
__global__ __launch_bounds__(256, 3) void kan_gemm2(
    const ushort_t* __restrict__ Xf, const ushort_t* __restrict__ Bt,
    float* __restrict__ out) {
    __shared__ ushort_t A_lds[2][4][4][64][8];   // 32 KB: [buf][ks][m][lane][8]

    int d = blockIdx.x;
    int g = d >> 5, r = d & 31;
    int bm = g * 8 + (r & 7), bn = r >> 3;
    if (bm >= 157) return;
    int tid = threadIdx.x, w = tid >> 6, l = tid & 63;
    int wc16 = bn * 8 + w * 2;

    f32x4 acc[4][2];
    #pragma unroll
    for (int m = 0; m < 4; ++m)
        #pragma unroll
        for (int nf = 0; nf < 2; ++nf)
            acc[m][nf] = (f32x4){0.f, 0.f, 0.f, 0.f};

    short8 b0[8], b1[8];

    auto stage = [&](int j, int pb) {            // A-tile for K-step j (4 kbs)
        #pragma unroll
        for (int ks = 0; ks < 4; ++ks) {
            const ushort_t* src = Xf + (((size_t)(bm * 4 + w) * NBK + 4 * j + ks) * 64 + l) * 8;
            __builtin_amdgcn_global_load_lds(
                (const __attribute__((address_space(1))) unsigned int*)src,
                (__attribute__((address_space(3))) unsigned int*)&A_lds[pb][ks][w][0][0],
                16, 0, 0);
        }
    };
    auto loadB = [&](int j, short8 (&b)[8]) {
        #pragma unroll
        for (int ks = 0; ks < 4; ++ks) {
            int kb = 4 * j + ks;
            b[ks * 2 + 0] = *(const short8*)(Bt + ((size_t)(kb * 32 + wc16)     * 64 + l) * 8);
            b[ks * 2 + 1] = *(const short8*)(Bt + ((size_t)(kb * 32 + wc16 + 1) * 64 + l) * 8);
        }
    };
    auto compute = [&](int pb, short8 (&b)[8]) {
        #pragma unroll
        for (int ks = 0; ks < 4; ++ks)
            #pragma unroll
            for (int m = 0; m < 4; ++m) {
                short8 af = *(const short8*)&A_lds[pb][ks][m][l][0];
                acc[m][0] = __builtin_amdgcn_mfma_f32_16x16x32_bf16(af, b[ks * 2 + 0], acc[m][0], 0, 0, 0);
                acc[m][1] = __builtin_amdgcn_mfma_f32_16x16x32_bf16(af, b[ks * 2 + 1], acc[m][1], 0, 0, 0);
            }
    };

    stage(0, 0);
    loadB(0, b0);
    __syncthreads();
    for (int j = 0; j < 36; j += 2) {
        if (j + 1 < 36) { stage(j + 1, 1); loadB(j + 1, b1); }
        compute(0, b0);
        __syncthreads();
        if (j + 2 < 36) { stage(j + 2, 0); loadB(j + 2, b0); }
        compute(1, b1);
        __syncthreads();
    }

    // store: C/D layout col = l&15, row = (l>>4)*4 + reg
    #pragma unroll
    for (int m = 0; m < 4; ++m) {
        int r0 = bm * 64 + m * 16 + ((l >> 4) << 2);
        #pragma unroll
        for (int nf = 0; nf < 2; ++nf) {
            int colg = bn * 128 + w * 32 + nf * 16 + (l & 15);
            #pragma unroll
            for (int jr = 0; jr < 4; ++jr) {
                int rr = r0 + jr;
                if (rr < N_NODES) out[(size_t)rr * OUT_F + colg] = acc[m][nf][jr];
            }
        }
    }
}

extern "C" void kernel_launch(void* const* d_in, const int* in_sizes, int n_in,
                              void* d_out, int out_size, void* d_ws, size_t ws_size,
                              hipStream_t stream) {
    const float* h        = (const float*)d_in[0];
    const float* W        = (const float*)d_in[1];
    const float* a        = (const float*)d_in[2];
    const float* base_w   = (const float*)d_in[3];
    const float* spline_w = (const float*)d_in[4];
    const int*   ei       = (const int*)d_in[5];
    float* out = (float*)d_out;

    char* ws = (char*)d_ws;
    size_t cur = 0;
    auto alloc = [&](size_t bytes) -> void* {
        void* p = ws + cur;
        cur += (bytes + 255) & ~(size_t)255;
        return p;
    };
    float* wa0    = (float*)alloc(512 * 4);
    float* wa1    = (float*)alloc(512 * 4);
    float* s      = (float*)alloc(N_NODES * 4);
    float* t      = (float*)alloc(N_NODES * 4);
    int*   deg    = (int*)alloc(N_NODES * 4);
    int*   offp   = (int*)alloc((N_NODES + 1) * 4);
    int*   cursor = (int*)alloc(N_NODES * 4);
    int*   csr    = (int*)alloc(N_EDGES * 4);
    float* agg    = (float*)alloc((size_t)N_NODES * IN_F * 4);
    ushort_t* Bt  = (ushort_t*)alloc((size_t)K_TOTAL * OUT_F * 2);
    ushort_t* hb  = (ushort_t*)alloc((size_t)N_NODES * IN_F * 2);
    ushort_t* Xf  = (ushort_t*)alloc((size_t)NBM * NBK * 64 * 16);
    if (cur > ws_size) return;

    hipMemsetAsync(deg, 0, N_NODES * 4, stream);
    wa_kernel<<<128, 256, 0, stream>>>(W, a, wa0, wa1);
    fused1_kernel<<<4277, 256, 0, stream>>>(h, hb, wa0, wa1, s, t, base_w, spline_w, Bt, ei, deg);
    scan_kernel<<<1, 256, 0, stream>>>(deg, offp, cursor);
    fill_kernel<<<625, 256, 0, stream>>>(ei, cursor, csr);
    agg_kernel<<<2500, 256, 0, stream>>>(hb, s, t, offp, csr, agg);
    expand_kernel<<<628, 256, 0, stream>>>(agg, Xf);
    kan_gemm2<<<640, 256, 0, stream>>>(Xf, Bt, out);
}

// Round 17
// 161.065 us; speedup vs baseline: 1.0282x; 1.0282x over previous
//
#include <hip/hip_runtime.h>
#include <hip/hip_bf16.h>
#include <math.h>

#define N_NODES 10000
#define IN_F 512
#define OUT_F 512
#define N_EDGES 160000
#define K_SPLINE 4096   // 512 dims * 8 basis fns
#define K_TOTAL 4608    // + 512 silu(base) slots
#define NBK 144         // K fragment-blocks (4608/32)
#define NBM 628         // M fragment-blocks (157 tiles * 4)
#define ALPHA 0.2f

typedef __attribute__((ext_vector_type(8))) short short8;
typedef __attribute__((ext_vector_type(4))) float f32x4;
typedef unsigned short ushort_t;
typedef unsigned long long u64;

__device__ __forceinline__ unsigned bfpair(float a, float b) {
    __hip_bfloat162 h2 = __float22bfloat162_rn(make_float2(a, b));
    return *reinterpret_cast<unsigned*>(&h2);
}
__device__ __forceinline__ float bflo(unsigned u) { return __uint_as_float(u << 16); }
__device__ __forceinline__ float bfhi(unsigned u) { return __uint_as_float(u & 0xffff0000u); }

__device__ __forceinline__ float silu_f(float x) {
    return x / (1.f + __expf(-x));
}

// spline window: 8 packed bf16 (one-hot shifted cubic pieces) for scalar x
__device__ __forceinline__ uint4 spline_window(float x) {
    float xc = (x + 2.2f) * 2.5f;
    float fc = floorf(xc);
    int c = (int)fc;
    float u = xc - fc;
    float omu = 1.f - u;
    float u2 = u * u, u3 = u2 * u;
    float n0 = (1.f / 6.f) * omu * omu * omu;
    float n1 = 0.5f * u3 - u2 + (2.f / 3.f);
    float n2 = -0.5f * u3 + 0.5f * u2 + 0.5f * u + (1.f / 6.f);
    float n3 = (1.f / 6.f) * u3;
    u64 V = (u64)bfpair(n0, n1) | ((u64)bfpair(n2, n3) << 32);
    int sh = (c - 3) * 16;
    u64 lo, hi;
    if (c < 0 || c > 10)    { lo = 0; hi = 0; }
    else if (sh >= 64)      { lo = 0; hi = V << (sh - 64); }
    else if (sh > 0)        { lo = V << sh; hi = V >> (64 - sh); }
    else if (sh == 0)       { lo = V; hi = 0; }
    else                    { lo = V >> (-sh); hi = 0; }
    uint4 pk;
    pk.x = (unsigned)lo; pk.y = (unsigned)(lo >> 32);
    pk.z = (unsigned)hi; pk.w = (unsigned)(hi >> 32);
    return pk;
}

// ---------------- K0: wa projections + deg zeroing ----------------
__global__ void wa_deg_kernel(const float* __restrict__ W, const float* __restrict__ a,
                              float* __restrict__ wa0, float* __restrict__ wa1,
                              int* __restrict__ deg) {
    int b = blockIdx.x;
    int tid = threadIdx.x;
    if (b < 128) {
        int w = tid >> 6, l = tid & 63;
        int i = b * 4 + w;
        float s0 = 0.f, s1 = 0.f;
        #pragma unroll
        for (int oo = 0; oo < 8; ++oo) {
            int o = l + oo * 64;
            float wv = W[(size_t)i * OUT_F + o];
            s0 += wv * a[o];
            s1 += wv * a[OUT_F + o];
        }
        #pragma unroll
        for (int off = 32; off > 0; off >>= 1) {
            s0 += __shfl_down(s0, off, 64);
            s1 += __shfl_down(s1, off, 64);
        }
        if (l == 0) { wa0[i] = s0; wa1[i] = s1; }
    } else {
        int idx = (b - 128) * 256 + tid;
        if (idx < N_NODES) deg[idx] = 0;
    }
}

// ---------------- K1: fused deg-hist + (hcast & s,t projections) + packB ----------------
__global__ void fused1_kernel(const float* __restrict__ h, ushort_t* __restrict__ hb,
                              const float* __restrict__ wa0, const float* __restrict__ wa1,
                              float* __restrict__ s, float* __restrict__ t,
                              const float* __restrict__ base_w, const float* __restrict__ spline_w,
                              ushort_t* __restrict__ Bt,
                              const int* __restrict__ ei, int* __restrict__ deg) {
    int b = blockIdx.x;
    int tid = threadIdx.x;
    if (b < 625) {
        int k = b * 256 + tid;
        if (k < N_EDGES) atomicAdd(&deg[ei[k]], 1);
    } else if (b < 3125) {
        int bb = b - 625;
        int w = tid >> 6, l = tid & 63;
        int n = bb * 4 + w;
        const float* hp = h + (size_t)n * IN_F + l * 8;
        float4 x0 = *(const float4*)hp;
        float4 x1 = *(const float4*)(hp + 4);
        uint4 pk;
        pk.x = bfpair(x0.x, x0.y);
        pk.y = bfpair(x0.z, x0.w);
        pk.z = bfpair(x1.x, x1.y);
        pk.w = bfpair(x1.z, x1.w);
        *(uint4*)(hb + (size_t)n * IN_F + l * 8) = pk;
        const float4* w0 = (const float4*)(wa0 + l * 8);
        const float4* w1 = (const float4*)(wa1 + l * 8);
        float4 a0 = w0[0], a1 = w0[1];
        float4 b0 = w1[0], b1 = w1[1];
        float ss = x0.x*a0.x + x0.y*a0.y + x0.z*a0.z + x0.w*a0.w
                 + x1.x*a1.x + x1.y*a1.y + x1.z*a1.z + x1.w*a1.w;
        float tt = x0.x*b0.x + x0.y*b0.y + x0.z*b0.z + x0.w*b0.w
                 + x1.x*b1.x + x1.y*b1.y + x1.z*b1.z + x1.w*b1.w;
        #pragma unroll
        for (int o = 32; o > 0; o >>= 1) {
            ss += __shfl_down(ss, o, 64);
            tt += __shfl_down(tt, o, 64);
        }
        if (l == 0) { s[n] = ss; t[n] = tt; }
    } else {
        int gid = (b - 3125) * 256 + tid;       // 294912 = 512 o * 576 kb8
        int o = gid / 576;
        int kb8 = gid - o * 576;
        int k0 = kb8 * 8;
        float4 x0, x1;
        if (k0 < K_SPLINE) {
            const float4* p = (const float4*)(spline_w + (size_t)o * K_SPLINE + k0);
            x0 = p[0]; x1 = p[1];
        } else {
            const float4* p = (const float4*)(base_w + (size_t)o * IN_F + (k0 - K_SPLINE));
            x0 = p[0]; x1 = p[1];
        }
        int frag = (k0 >> 5) * 32 + (o >> 4);
        int lane = ((kb8 & 3) << 4) + (o & 15);
        uint4 pk;
        pk.x = bfpair(x0.x, x0.y);
        pk.y = bfpair(x0.z, x0.w);
        pk.z = bfpair(x1.x, x1.y);
        pk.w = bfpair(x1.z, x1.w);
        *(uint4*)(Bt + ((size_t)frag * 64 + lane) * 8) = pk;
    }
}

// ---------------- K2: one-block exclusive scan over degrees ----------------
__global__ void scan_kernel(const int* __restrict__ deg, int* __restrict__ off,
                            int* __restrict__ cursor) {
    __shared__ int sb[256];
    int tid = threadIdx.x;
    int d[40];
    int tot = 0;
    #pragma unroll
    for (int j = 0; j < 40; ++j) {
        int idx = tid * 40 + j;
        d[j] = (idx < N_NODES) ? deg[idx] : 0;
        tot += d[j];
    }
    sb[tid] = tot;
    __syncthreads();
    for (int sd = 1; sd < 256; sd <<= 1) {
        int v = (tid >= sd) ? sb[tid - sd] : 0;
        __syncthreads();
        sb[tid] += v;
        __syncthreads();
    }
    int run = (tid > 0) ? sb[tid - 1] : 0;
    #pragma unroll
    for (int j = 0; j < 40; ++j) {
        int idx = tid * 40 + j;
        if (idx < N_NODES) { off[idx] = run; cursor[idx] = run; }
        run += d[j];
    }
    if (tid == 255) off[N_NODES] = sb[255];
}

// ---------------- K3: fill CSR ----------------
__global__ void fill_kernel(const int* __restrict__ ei, int* __restrict__ cursor,
                            int* __restrict__ csr_col) {
    int k = blockIdx.x * 256 + threadIdx.x;
    if (k < N_EDGES) {
        int r = ei[k];
        int c = ei[N_EDGES + k];
        int p = atomicAdd(&cursor[r], 1);
        csr_col[p] = c;
    }
}

// ---------------- K4: segment softmax + aggregation, wave-per-node, 2-way edge split ----------------
__global__ __launch_bounds__(256) void agg_kernel(
    const ushort_t* __restrict__ hb, const float* __restrict__ s,
    const float* __restrict__ t, const int* __restrict__ off,
    const int* __restrict__ csr, float* __restrict__ agg) {
    int w = threadIdx.x >> 6, l = threadIdx.x & 63;
    int n = blockIdx.x * 4 + w;
    int e0 = off[n], e1 = off[n + 1];
    float sn = s[n];

    float m = -1e30f, den = 0.f;
    for (int k = e0 + l; k < e1; k += 64) {
        float v = sn + t[csr[k]];
        v = (v >= 0.f) ? v : ALPHA * v;
        float mn = fmaxf(m, v);
        den = den * __expf(m - mn) + __expf(v - mn);
        m = mn;
    }
    #pragma unroll
    for (int o = 1; o < 64; o <<= 1) {
        float m2 = __shfl_xor(m, o, 64);
        float d2 = __shfl_xor(den, o, 64);
        float mn = fmaxf(m, m2);
        den = den * __expf(m - mn) + d2 * __expf(m2 - mn);
        m = mn;
    }
    float inv = (den > 0.f) ? 1.f / den : 0.f;

    int hl = l >> 5;
    int lo = l & 31;
    float acc[16];
    #pragma unroll
    for (int i = 0; i < 16; ++i) acc[i] = 0.f;
    const ushort_t* hbl = hb + lo * 16;

    for (int base = e0; base < e1; base += 64) {
        int cnt = e1 - base; if (cnt > 64) cnt = 64;
        int c = 0; float att = 0.f;
        if (l < cnt) {
            c = csr[base + l];
            float v = sn + t[c];
            v = (v >= 0.f) ? v : ALPHA * v;
            att = __expf(v - m) * inv;
        }
        int npair = (cnt + 1) >> 1;
        #pragma unroll 2
        for (int j = 0; j < npair; ++j) {
            int e = 2 * j + hl;
            float aj = __shfl(att, e, 64);
            int cj = __shfl(c, e, 64);
            const ushort_t* rp = hbl + (size_t)cj * IN_F;
            uint4 u0 = *(const uint4*)rp;
            uint4 u1 = *(const uint4*)(rp + 8);
            acc[0]  = fmaf(aj, bflo(u0.x), acc[0]);
            acc[1]  = fmaf(aj, bfhi(u0.x), acc[1]);
            acc[2]  = fmaf(aj, bflo(u0.y), acc[2]);
            acc[3]  = fmaf(aj, bfhi(u0.y), acc[3]);
            acc[4]  = fmaf(aj, bflo(u0.z), acc[4]);
            acc[5]  = fmaf(aj, bfhi(u0.z), acc[5]);
            acc[6]  = fmaf(aj, bflo(u0.w), acc[6]);
            acc[7]  = fmaf(aj, bfhi(u0.w), acc[7]);
            acc[8]  = fmaf(aj, bflo(u1.x), acc[8]);
            acc[9]  = fmaf(aj, bfhi(u1.x), acc[9]);
            acc[10] = fmaf(aj, bflo(u1.y), acc[10]);
            acc[11] = fmaf(aj, bfhi(u1.y), acc[11]);
            acc[12] = fmaf(aj, bflo(u1.z), acc[12]);
            acc[13] = fmaf(aj, bfhi(u1.z), acc[13]);
            acc[14] = fmaf(aj, bflo(u1.w), acc[14]);
            acc[15] = fmaf(aj, bfhi(u1.w), acc[15]);
        }
    }
    #pragma unroll
    for (int i = 0; i < 16; ++i) acc[i] += __shfl_xor(acc[i], 32, 64);

    if (hl == 0) {
        float* arow = agg + (size_t)n * IN_F + lo * 16;
        *(float4*)(arow)      = make_float4(acc[0],  acc[1],  acc[2],  acc[3]);
        *(float4*)(arow + 4)  = make_float4(acc[4],  acc[5],  acc[6],  acc[7]);
        *(float4*)(arow + 8)  = make_float4(acc[8],  acc[9],  acc[10], acc[11]);
        *(float4*)(arow + 12) = make_float4(acc[12], acc[13], acc[14], acc[15]);
    }
}

// ---------------- K5: LDS-staged expansion -> fragment-packed bf16 A ----------------
__global__ __launch_bounds__(256) void expand_kernel(const float* __restrict__ agg,
                                                     ushort_t* __restrict__ Xf) {
    __shared__ float AL[16][516];   // 33 KB; stride 516 keeps reads conflict-light
    int nb = blockIdx.x;
    int tid = threadIdx.x;

    #pragma unroll
    for (int i = 0; i < 8; ++i) {
        int idx = i * 256 + tid;        // 0..2047 float4 slots
        int r = idx >> 7, c4 = idx & 127;
        int n = nb * 16 + r;
        float4 v = (n < N_NODES) ? ((const float4*)(agg + (size_t)n * IN_F))[c4]
                                 : make_float4(0.f, 0.f, 0.f, 0.f);
        *(float4*)&AL[r][c4 * 4] = v;
    }
    __syncthreads();

    int w = tid >> 6, l = tid & 63;
    bool live = (nb * 16 + (l & 15)) < N_NODES;
    #pragma unroll 1
    for (int i = 0; i < 36; ++i) {
        int kb = w + 4 * i;             // wave w covers kb ≡ w (mod 4)
        uint4 pk = make_uint4(0u, 0u, 0u, 0u);
        if (live) {
            if (kb < 128) {
                int dim = kb * 4 + (l >> 4);
                pk = spline_window(AL[l & 15][dim]);
            } else {
                const float* ap = &AL[l & 15][(kb - 128) * 32 + (l >> 4) * 8];
                float4 x0 = *(const float4*)ap;
                float4 x1 = *(const float4*)(ap + 4);
                pk.x = bfpair(silu_f(x0.x), silu_f(x0.y));
                pk.y = bfpair(silu_f(x0.z), silu_f(x0.w));
                pk.z = bfpair(silu_f(x1.x), silu_f(x1.y));
                pk.w = bfpair(silu_f(x1.z), silu_f(x1.w));
            }
        }
        *(uint4*)(Xf + ((size_t)(nb * NBK + kb) * 64 + l) * 8) = pk;
    }
}

// ---------------- K6: streaming GEMM, BK=128, 2-phase double buffer (measured-best) ----------------
// BM=64, BN=128, 4 waves; 36 K-steps of 128; A via global_load_lds (16B);
// B direct L2->reg. Grid 640, R6 decode. 62.9-63.0 us across 6 reproductions;
// bracketed by: counted-vmcnt (neutral), K-split (net loss), BM=32 (+28%),
// BM=128 (+100%), stripe decodes (+23..90%), BK=64 (+4%). Structural plateau.
__global__ __launch_bounds__(256, 3) void kan_gemm2(
    const ushort_t* __restrict__ Xf, const ushort_t* __restrict__ Bt,
    float* __restrict__ out) {
    __shared__ ushort_t A_lds[2][4][4][64][8];   // 32 KB: [buf][ks][m][lane][8]

    int d = blockIdx.x;
    int g = d >> 5, r = d & 31;
    int bm = g * 8 + (r & 7), bn = r >> 3;
    if (bm >= 157) return;
    int tid = threadIdx.x, w = tid >> 6, l = tid & 63;
    int wc16 = bn * 8 + w * 2;

    f32x4 acc[4][2];
    #pragma unroll
    for (int m = 0; m < 4; ++m)
        #pragma unroll
        for (int nf = 0; nf < 2; ++nf)
            acc[m][nf] = (f32x4){0.f, 0.f, 0.f, 0.f};

    short8 b0[8], b1[8];

    auto stage = [&](int j, int pb) {            // A-tile for K-step j (4 kbs)
        #pragma unroll
        for (int ks = 0; ks < 4; ++ks) {
            const ushort_t* src = Xf + (((size_t)(bm * 4 + w) * NBK + 4 * j + ks) * 64 + l) * 8;
            __builtin_amdgcn_global_load_lds(
                (const __attribute__((address_space(1))) unsigned int*)src,
                (__attribute__((address_space(3))) unsigned int*)&A_lds[pb][ks][w][0][0],
                16, 0, 0);
        }
    };
    auto loadB = [&](int j, short8 (&b)[8]) {
        #pragma unroll
        for (int ks = 0; ks < 4; ++ks) {
            int kb = 4 * j + ks;
            b[ks * 2 + 0] = *(const short8*)(Bt + ((size_t)(kb * 32 + wc16)     * 64 + l) * 8);
            b[ks * 2 + 1] = *(const short8*)(Bt + ((size_t)(kb * 32 + wc16 + 1) * 64 + l) * 8);
        }
    };
    auto compute = [&](int pb, short8 (&b)[8]) {
        #pragma unroll
        for (int ks = 0; ks < 4; ++ks)
            #pragma unroll
            for (int m = 0; m < 4; ++m) {
                short8 af = *(const short8*)&A_lds[pb][ks][m][l][0];
                acc[m][0] = __builtin_amdgcn_mfma_f32_16x16x32_bf16(af, b[ks * 2 + 0], acc[m][0], 0, 0, 0);
                acc[m][1] = __builtin_amdgcn_mfma_f32_16x16x32_bf16(af, b[ks * 2 + 1], acc[m][1], 0, 0, 0);
            }
    };

    stage(0, 0);
    loadB(0, b0);
    __syncthreads();
    for (int j = 0; j < 36; j += 2) {
        if (j + 1 < 36) { stage(j + 1, 1); loadB(j + 1, b1); }
        compute(0, b0);
        __syncthreads();
        if (j + 2 < 36) { stage(j + 2, 0); loadB(j + 2, b0); }
        compute(1, b1);
        __syncthreads();
    }

    // store: C/D layout col = l&15, row = (l>>4)*4 + reg
    #pragma unroll
    for (int m = 0; m < 4; ++m) {
        int r0 = bm * 64 + m * 16 + ((l >> 4) << 2);
        #pragma unroll
        for (int nf = 0; nf < 2; ++nf) {
            int colg = bn * 128 + w * 32 + nf * 16 + (l & 15);
            #pragma unroll
            for (int jr = 0; jr < 4; ++jr) {
                int rr = r0 + jr;
                if (rr < N_NODES) out[(size_t)rr * OUT_F + colg] = acc[m][nf][jr];
            }
        }
    }
}

extern "C" void kernel_launch(void* const* d_in, const int* in_sizes, int n_in,
                              void* d_out, int out_size, void* d_ws, size_t ws_size,
                              hipStream_t stream) {
    const float* h        = (const float*)d_in[0];
    const float* W        = (const float*)d_in[1];
    const float* a        = (const float*)d_in[2];
    const float* base_w   = (const float*)d_in[3];
    const float* spline_w = (const float*)d_in[4];
    const int*   ei       = (const int*)d_in[5];
    float* out = (float*)d_out;

    char* ws = (char*)d_ws;
    size_t cur = 0;
    auto alloc = [&](size_t bytes) -> void* {
        void* p = ws + cur;
        cur += (bytes + 255) & ~(size_t)255;
        return p;
    };
    float* wa0    = (float*)alloc(512 * 4);
    float* wa1    = (float*)alloc(512 * 4);
    float* s      = (float*)alloc(N_NODES * 4);
    float* t      = (float*)alloc(N_NODES * 4);
    int*   deg    = (int*)alloc(N_NODES * 4);
    int*   offp   = (int*)alloc((N_NODES + 1) * 4);
    int*   cursor = (int*)alloc(N_NODES * 4);
    int*   csr    = (int*)alloc(N_EDGES * 4);
    float* agg    = (float*)alloc((size_t)N_NODES * IN_F * 4);
    ushort_t* Bt  = (ushort_t*)alloc((size_t)K_TOTAL * OUT_F * 2);
    ushort_t* hb  = (ushort_t*)alloc((size_t)N_NODES * IN_F * 2);
    ushort_t* Xf  = (ushort_t*)alloc((size_t)NBM * NBK * 64 * 16);
    if (cur > ws_size) return;

    wa_deg_kernel<<<168, 256, 0, stream>>>(W, a, wa0, wa1, deg);
    fused1_kernel<<<4277, 256, 0, stream>>>(h, hb, wa0, wa1, s, t, base_w, spline_w, Bt, ei, deg);
    scan_kernel<<<1, 256, 0, stream>>>(deg, offp, cursor);
    fill_kernel<<<625, 256, 0, stream>>>(ei, cursor, csr);
    agg_kernel<<<2500, 256, 0, stream>>>(hb, s, t, offp, csr, agg);
    expand_kernel<<<628, 256, 0, stream>>>(agg, Xf);
    kan_gemm2<<<640, 256, 0, stream>>>(Xf, Bt, out);
}